// Round 6
// baseline (361.147 us; speedup 1.0000x reference)
//
#include <hip/hip_runtime.h>
#include <stdint.h>

#define BB 4096
#define TT 512
#define HH 32
#define SS 4

typedef float v2f __attribute__((ext_vector_type(2)));

__device__ __forceinline__ float fast_sigm(float a) {
  return __builtin_amdgcn_rcpf(1.0f + __expf(-a));      // v_exp + v_rcp
}
__device__ __forceinline__ float fast_tanh(float y) {
  return 1.0f - 2.0f * __builtin_amdgcn_rcpf(__expf(2.0f * y) + 1.0f);
}
// packed 2xf32 FMA (VOP3P v_pk_fma_f32): c = a*b + c, element-wise
__device__ __forceinline__ v2f pkfma(v2f a, v2f b, v2f c) {
  asm("v_pk_fma_f32 %0, %1, %2, %0" : "+v"(c) : "v"(a), "v"(b));
  return c;
}

// One batch per 64-lane wave: lane = (j = h-row 0..31, half = K-half 0..1).
// Lane holds w_{r,z,n}[j][16*half .. 16*half+15] (48 regs) -> fits 128-VGPR
// budget -> 4 waves/SIMD. Hidden GEMV: 24 pk_fma/lane; cross-half reduce via
// 3 shfl_xor(32). h broadcast via per-wave LDS row (same-wave in-order DS).
__global__ __launch_bounds__(256, 4) void gru_kernel(
    const float* __restrict__ x, const float* __restrict__ h0,
    const float* __restrict__ w_ih, const float* __restrict__ w_hh,
    const float* __restrict__ b_ih, const float* __restrict__ b_hh,
    const float* __restrict__ w_proj, const float* __restrict__ b_proj,
    float* __restrict__ out) {
  const int tid  = threadIdx.x;
  const int wid  = tid >> 6;        // wave in block 0..3
  const int lane = tid & 63;
  const int j    = lane & 31;       // h row this lane owns
  const int half = lane >> 5;       // K-half this lane covers
  const int b    = blockIdx.x * 4 + wid;

  __shared__ float lds_h[4][36];    // one 32-float row per wave (+4 pad)
  float* lrow = &lds_h[wid][0];

  // ---- preload hidden weights: 8 float2 per gate per lane ----
  const float4* whh4 = (const float4*)w_hh;      // [96][8] float4
  v2f wr2[8], wz2[8], wn2[8];
#pragma unroll
  for (int c = 0; c < 4; ++c) {
    float4 q;
    q = whh4[(0 * HH + j) * 8 + half * 4 + c];
    wr2[2*c] = (v2f){q.x, q.y}; wr2[2*c+1] = (v2f){q.z, q.w};
    q = whh4[(1 * HH + j) * 8 + half * 4 + c];
    wz2[2*c] = (v2f){q.x, q.y}; wz2[2*c+1] = (v2f){q.z, q.w};
    q = whh4[(2 * HH + j) * 8 + half * 4 + c];
    wn2[2*c] = (v2f){q.x, q.y}; wn2[2*c+1] = (v2f){q.z, q.w};
  }
#pragma unroll
  for (int m = 0; m < 8; ++m) {     // discourage load-sinking (cheap insurance)
    asm("" : "+v"(wr2[m]), "+v"(wz2[m]), "+v"(wn2[m]));
  }

  const float4* wih4 = (const float4*)w_ih;      // row = one float4 (I=4)
  const float4 wir = wih4[0 * HH + j];
  const float4 wiz = wih4[1 * HH + j];
  const float4 win = wih4[2 * HH + j];
  const float bir = b_ih[0*HH + j], biz = b_ih[1*HH + j], bin_ = b_ih[2*HH + j];
  const float bhr = b_hh[0*HH + j], bhz = b_hh[1*HH + j], bhn = b_hh[2*HH + j];

  const int s_idx = j & 3;          // proj channel this lane reduces
  const int c_idx = j >> 2;         // h-chunk (of 8) this lane covers
  const float4* wp4 = (const float4*)w_proj;     // [4][8] float4
  const float4 wp = wp4[s_idx * 8 + c_idx];
  const float bp = b_proj[s_idx];

  float h_self = h0[(size_t)b * HH + j];
  lrow[j] = h_self;                 // both halves write identical value: ok

  const float4* xp = (const float4*)(x + (size_t)b * TT * 4);  // 512 float4
  float* outp = out + (size_t)b * TT * SS;
  const float* hk_addr = lrow + half * 16;       // this lane's K-half base
  const float* hc_addr = lrow + (c_idx << 2);    // this lane's proj chunk

  for (int t = 0; t <= TT; ++t) {
    // broadcast-read h_{t-1}: this lane's K-half (4x b128, 2 addrs/wave) and
    // its proj chunk (1x b128, 8 addrs/wave; all same-addr lanes broadcast)
    v2f h2[8];
#pragma unroll
    for (int c = 0; c < 4; ++c) {
      const float4 q = *(const float4*)(hk_addr + 4 * c);
      h2[2*c] = (v2f){q.x, q.y}; h2[2*c+1] = (v2f){q.z, q.w};
    }
    const float4 hcv = *(const float4*)hc_addr;

    // deferred projection: out[t-1] = proj(h_{t-1})
    if (t > 0) {
      float v = fmaf(wp.x, hcv.x, fmaf(wp.y, hcv.y,
                fmaf(wp.z, hcv.z, wp.w * hcv.w)));
      v += __shfl_xor(v, 4, 64);
      v += __shfl_xor(v, 8, 64);
      v += __shfl_xor(v, 16, 64);
      if (lane < 4) {               // c_idx==0 && half==0; s_idx == lane
        outp[(t - 1) * SS + lane] = v + bp;
      }
    }
    if (t == TT) break;

    const float4 xv = xp[t];        // wave-uniform address (broadcast load)

    // input-gate contributions (I=4), per-j
    float xr = fmaf(wir.x, xv.x, fmaf(wir.y, xv.y, fmaf(wir.z, xv.z, fmaf(wir.w, xv.w, bir))));
    float xz = fmaf(wiz.x, xv.x, fmaf(wiz.y, xv.y, fmaf(wiz.z, xv.z, fmaf(wiz.w, xv.w, biz))));
    float xn = fmaf(win.x, xv.x, fmaf(win.y, xv.y, fmaf(win.z, xv.z, fmaf(win.w, xv.w, bin_))));

    // hidden-gate partials over this lane's 16 h-values: 24 pk_fma
    v2f aR = (v2f){0.f, 0.f}, aZ = (v2f){0.f, 0.f}, aN = (v2f){0.f, 0.f};
#pragma unroll
    for (int m = 0; m < 8; ++m) {
      aR = pkfma(wr2[m], h2[m], aR);
      aZ = pkfma(wz2[m], h2[m], aZ);
      aN = pkfma(wn2[m], h2[m], aN);
    }
    float hrp = aR.x + aR.y, hzp = aZ.x + aZ.y, hnp = aN.x + aN.y;
    // cross-half reduce (commutative 2-addend sum -> bit-identical in halves)
    const float hr = hrp + __shfl_xor(hrp, 32, 64) + bhr;
    const float hz = hzp + __shfl_xor(hzp, 32, 64) + bhz;
    const float hn = hnp + __shfl_xor(hnp, 32, 64) + bhn;

    const float r  = fast_sigm(xr + hr);
    const float zz = fast_sigm(xz + hz);
    const float nn = fast_tanh(fmaf(r, hn, xn));
    const float hnew = fmaf(zz, h_self - nn, nn);  // (1-z)n + z h
    h_self = hnew;

    // publish h_t: both halves store the identical value to lrow[j]
    lrow[j] = hnew;
  }

  // hn output: [1, B, H] appended after state (float32)
  if (half == 0) {
    out[(size_t)BB * TT * SS + (size_t)b * HH + j] = h_self;
  }
}

extern "C" void kernel_launch(void* const* d_in, const int* in_sizes, int n_in,
                              void* d_out, int out_size, void* d_ws, size_t ws_size,
                              hipStream_t stream) {
  const float* x      = (const float*)d_in[0];
  const float* h0     = (const float*)d_in[1];
  const float* w_ih   = (const float*)d_in[2];
  const float* w_hh   = (const float*)d_in[3];
  const float* b_ih   = (const float*)d_in[4];
  const float* b_hh   = (const float*)d_in[5];
  const float* w_proj = (const float*)d_in[6];
  const float* b_proj = (const float*)d_in[7];
  float* out = (float*)d_out;

  dim3 grid(BB / 4), block(256);
  hipLaunchKernelGGL(gru_kernel, grid, block, 0, stream,
                     x, h0, w_ih, w_hh, b_ih, b_hh, w_proj, b_proj, out);
}

// Round 7
// 291.874 us; speedup vs baseline: 1.2373x; 1.2373x over previous
//
#include <hip/hip_runtime.h>
#include <stdint.h>

#define BB 4096
#define TT 512
#define HH 32
#define SS 4

typedef float v2f __attribute__((ext_vector_type(2)));

#define STR2(x) #x
#define STR(x) STR2(x)
// Non-sinkable, non-rematerializable loads: compiler must keep results live.
#define GLOAD4(dst, ptr, off)                                                  \
  asm volatile("global_load_dwordx4 %0, %1, off offset:" STR(off)              \
               : "=v"(dst) : "v"(ptr))
#define GLOAD1(dst, ptr, off)                                                  \
  asm volatile("global_load_dword %0, %1, off offset:" STR(off)                \
               : "=v"(dst) : "v"(ptr))

__device__ __forceinline__ float fast_sigm(float a) {
  return __builtin_amdgcn_rcpf(1.0f + __expf(-a));      // v_exp + v_rcp
}
__device__ __forceinline__ float fast_tanh(float y) {
  return 1.0f - 2.0f * __builtin_amdgcn_rcpf(__expf(2.0f * y) + 1.0f);
}
// packed 2xf32 FMA (VOP3P): c = a*b + c elementwise
__device__ __forceinline__ v2f pkfma(v2f a, v2f b, v2f c) {
  asm("v_pk_fma_f32 %0, %1, %2, %0" : "+v"(c) : "v"(a), "v"(b));
  return c;
}

// Round-5 layout (best so far): 32 lanes per batch (lane j owns h[j]),
// 2 batches/wave, 4 waves/block. Weights asm-volatile-loaded -> VGPR-resident.
// Hidden GEMV as 48 v_pk_fma_f32. h broadcast via per-batch LDS row
// (same-wave write->read, in-order DS pipe, validated rounds 3-5).
__global__ __launch_bounds__(256, 2) void gru_kernel(
    const float* __restrict__ x, const float* __restrict__ h0,
    const float* __restrict__ w_ih, const float* __restrict__ w_hh,
    const float* __restrict__ b_ih, const float* __restrict__ b_hh,
    const float* __restrict__ w_proj, const float* __restrict__ b_proj,
    float* __restrict__ out) {
  const int tid  = threadIdx.x;
  const int wid  = tid >> 6;        // wave in block 0..3
  const int lane = tid & 63;
  const int g    = lane >> 5;       // which batch of the wave's two
  const int j    = lane & 31;       // h index owned by this lane
  const int row  = wid * 2 + g;     // LDS row 0..7
  const int b    = blockIdx.x * 8 + row;

  __shared__ float lds_h[8][36];    // 144B row stride: conflict-free (see r5)
  float* lrow = &lds_h[row][0];

  const int s_idx = j & 3;          // proj channel this lane reduces
  const int c_idx = j >> 2;         // h-chunk (of 8) this lane covers

  // ---- asm-volatile preload of ALL loop-invariant parameters ----
  float4 wq[24];                    // w_hh rows j, j+32, j+64 (96 floats)
  float4 wih_r, wih_z, wih_n;       // w_ih rows (I=4 -> one float4 each)
  float4 wp;                        // w_proj row chunk
  float bir, biz, bin_, bhr, bhz, bhn, bp;
  {
    const char* p0 = (const char*)(w_hh + (0 * HH + j) * HH);
    const char* p1 = (const char*)(w_hh + (1 * HH + j) * HH);
    const char* p2 = (const char*)(w_hh + (2 * HH + j) * HH);
    GLOAD4(wq[0],  p0, 0);  GLOAD4(wq[1],  p0, 16);
    GLOAD4(wq[2],  p0, 32); GLOAD4(wq[3],  p0, 48);
    GLOAD4(wq[4],  p0, 64); GLOAD4(wq[5],  p0, 80);
    GLOAD4(wq[6],  p0, 96); GLOAD4(wq[7],  p0, 112);
    GLOAD4(wq[8],  p1, 0);  GLOAD4(wq[9],  p1, 16);
    GLOAD4(wq[10], p1, 32); GLOAD4(wq[11], p1, 48);
    GLOAD4(wq[12], p1, 64); GLOAD4(wq[13], p1, 80);
    GLOAD4(wq[14], p1, 96); GLOAD4(wq[15], p1, 112);
    GLOAD4(wq[16], p2, 0);  GLOAD4(wq[17], p2, 16);
    GLOAD4(wq[18], p2, 32); GLOAD4(wq[19], p2, 48);
    GLOAD4(wq[20], p2, 64); GLOAD4(wq[21], p2, 80);
    GLOAD4(wq[22], p2, 96); GLOAD4(wq[23], p2, 112);
    const char* pi = (const char*)(w_ih + j * 4);   // gate stride 32 rows*16B=512B
    GLOAD4(wih_r, pi, 0); GLOAD4(wih_z, pi, 512); GLOAD4(wih_n, pi, 1024);
    const char* pbi = (const char*)(b_ih + j);      // gate stride 128B
    GLOAD1(bir, pbi, 0); GLOAD1(biz, pbi, 128); GLOAD1(bin_, pbi, 256);
    const char* pbh = (const char*)(b_hh + j);
    GLOAD1(bhr, pbh, 0); GLOAD1(bhz, pbh, 128); GLOAD1(bhn, pbh, 256);
    const char* pp = (const char*)(w_proj + (s_idx * 8 + c_idx) * 4);
    GLOAD4(wp, pp, 0);
    const char* pbp = (const char*)(b_proj + s_idx);
    GLOAD1(bp, pbp, 0);
    asm volatile("s_waitcnt vmcnt(0)" ::: "memory");
    __builtin_amdgcn_sched_barrier(0);
  }

  // View the 96 w_hh floats as 48 v2f pairs (register aliasing, no moves)
  v2f wr2[16], wz2[16], wn2[16];
#pragma unroll
  for (int c = 0; c < 8; ++c) {
    wr2[2*c] = (v2f){wq[c].x,    wq[c].y};    wr2[2*c+1] = (v2f){wq[c].z,    wq[c].w};
    wz2[2*c] = (v2f){wq[8+c].x,  wq[8+c].y};  wz2[2*c+1] = (v2f){wq[8+c].z,  wq[8+c].w};
    wn2[2*c] = (v2f){wq[16+c].x, wq[16+c].y}; wn2[2*c+1] = (v2f){wq[16+c].z, wq[16+c].w};
  }

  float h_self = h0[(size_t)b * HH + j];
  lrow[j] = h_self;

  const float4* xp = (const float4*)(x + (size_t)b * TT * 4);  // 512 float4
  float* outp = out + (size_t)b * TT * SS;
  const float* hc_addr = lrow + (c_idx << 2);

  float4 xv = xp[0];

  for (int t = 0; t <= TT; ++t) {
    // broadcast-read h_{t-1}: 8x b128 (2 addrs/wave) + proj chunk (b128)
    v2f h2[16];
#pragma unroll
    for (int c = 0; c < 8; ++c) {
      const float4 q = *(const float4*)(lrow + 4 * c);
      h2[2*c] = (v2f){q.x, q.y}; h2[2*c+1] = (v2f){q.z, q.w};
    }
    const float4 hcv = *(const float4*)hc_addr;

    // deferred projection: out[t-1] = proj(h_{t-1})
    if (t > 0) {
      float v = fmaf(wp.x, hcv.x, fmaf(wp.y, hcv.y,
                fmaf(wp.z, hcv.z, wp.w * hcv.w)));
      v += __shfl_xor(v, 4, 64);
      v += __shfl_xor(v, 8, 64);
      v += __shfl_xor(v, 16, 64);
      if (c_idx == 0) {
        outp[(t - 1) * SS + s_idx] = v + bp;
      }
    }
    if (t == TT) break;

    float4 xvn = xp[(t + 1 < TT) ? (t + 1) : t];   // next-step x prefetch

    // input-gate contributions (I=4)
    float xr = fmaf(wih_r.x, xv.x, fmaf(wih_r.y, xv.y, fmaf(wih_r.z, xv.z, fmaf(wih_r.w, xv.w, bir))));
    float xz = fmaf(wih_z.x, xv.x, fmaf(wih_z.y, xv.y, fmaf(wih_z.z, xv.z, fmaf(wih_z.w, xv.w, biz))));
    float xn = fmaf(wih_n.x, xv.x, fmaf(wih_n.y, xv.y, fmaf(wih_n.z, xv.z, fmaf(wih_n.w, xv.w, bin_))));

    // hidden-gate contributions: 48 packed FMAs, bias folded into init
    v2f aR = (v2f){bhr, 0.f}, aZ = (v2f){bhz, 0.f}, aN = (v2f){bhn, 0.f};
#pragma unroll
    for (int m = 0; m < 16; ++m) {
      aR = pkfma(wr2[m], h2[m], aR);
      aZ = pkfma(wz2[m], h2[m], aZ);
      aN = pkfma(wn2[m], h2[m], aN);
    }
    const float hr = aR.x + aR.y;
    const float hz = aZ.x + aZ.y;
    const float hn = aN.x + aN.y;

    const float r  = fast_sigm(xr + hr);
    const float zz = fast_sigm(xz + hz);
    const float nn = fast_tanh(fmaf(r, hn, xn));
    const float hnew = fmaf(zz, h_self - nn, nn);  // (1-z)n + z h
    h_self = hnew;

    lrow[j] = hnew;   // publish h_t (same-wave, in-order DS pipe)

    xv = xvn;
  }

  // hn output: [1, B, H] appended after state (float32)
  out[(size_t)BB * TT * SS + (size_t)b * HH + j] = h_self;
}

extern "C" void kernel_launch(void* const* d_in, const int* in_sizes, int n_in,
                              void* d_out, int out_size, void* d_ws, size_t ws_size,
                              hipStream_t stream) {
  const float* x      = (const float*)d_in[0];
  const float* h0     = (const float*)d_in[1];
  const float* w_ih   = (const float*)d_in[2];
  const float* w_hh   = (const float*)d_in[3];
  const float* b_ih   = (const float*)d_in[4];
  const float* b_hh   = (const float*)d_in[5];
  const float* w_proj = (const float*)d_in[6];
  const float* b_proj = (const float*)d_in[7];
  float* out = (float*)d_out;

  dim3 grid(BB / 8), block(256);
  hipLaunchKernelGGL(gru_kernel, grid, block, 0, stream,
                     x, h0, w_ih, w_hh, b_ih, b_hh, w_proj, b_proj, out);
}